// Round 2
// baseline (486.235 us; speedup 1.0000x reference)
//
#include <hip/hip_runtime.h>

#define N_TOK 4096
#define C_DIM 768
#define H_NUM 12
#define QKV_N 2304

typedef __attribute__((ext_vector_type(8))) short bf16x8;
typedef __attribute__((ext_vector_type(4))) float f32x4;

static __device__ __forceinline__ unsigned short f2bf(float f) {
  unsigned u = __builtin_bit_cast(unsigned, f);
  u += 0x7FFF + ((u >> 16) & 1);   // RNE
  return (unsigned short)(u >> 16);
}

// ---------------------------------------------------------------------------
// GEMM1: qkv = x @ w_qkv   (M=4096, K=768, N=2304), f32 in -> bf16 scatter out
// Q pre-scaled by 0.125; V stored transposed [H][64][N].
// ---------------------------------------------------------------------------
__global__ __launch_bounds__(256) void gemm_qkv(
    const float* __restrict__ x, const float* __restrict__ w,
    unsigned short* __restrict__ qw, unsigned short* __restrict__ kw,
    unsigned short* __restrict__ vw) {
  __shared__ unsigned short As[128 * 40];   // [m][k] pad 32->40
  __shared__ unsigned short Bs[128 * 40];   // [n][k] (transposed tile)
  const int t = threadIdx.x;
  const int lane = t & 63, wid = t >> 6;
  const int lr = lane & 15, lg = lane >> 4;
  const int m_base = blockIdx.y * 128, n_base = blockIdx.x * 128;
  const int wm = (wid >> 1) * 64, wn = (wid & 1) * 64;

  f32x4 acc[4][4];
#pragma unroll
  for (int mt = 0; mt < 4; ++mt)
#pragma unroll
    for (int nt = 0; nt < 4; ++nt) acc[mt][nt] = (f32x4){0.f, 0.f, 0.f, 0.f};

  for (int kt = 0; kt < 24; ++kt) {
    const int k0 = kt * 32;
    __syncthreads();
    // stage A: 128x32 f32 -> bf16
    {
      const int row = t >> 3, c4 = (t & 7) * 4;
#pragma unroll
      for (int rr = 0; rr < 4; ++rr) {
        const int r2 = rr * 32 + row;
        const float4 v = *reinterpret_cast<const float4*>(
            &x[(size_t)(m_base + r2) * 768 + k0 + c4]);
        unsigned short* d = &As[r2 * 40 + c4];
        d[0] = f2bf(v.x); d[1] = f2bf(v.y); d[2] = f2bf(v.z); d[3] = f2bf(v.w);
      }
    }
    // stage B transposed: 32x128 f32 -> bf16 [n][k]
    {
      const int kk0 = t >> 5, c4 = (t & 31) * 4;
#pragma unroll
      for (int rr = 0; rr < 4; ++rr) {
        const int kk = rr * 8 + kk0;
        const float4 v = *reinterpret_cast<const float4*>(
            &w[(size_t)(k0 + kk) * QKV_N + n_base + c4]);
        Bs[(c4 + 0) * 40 + kk] = f2bf(v.x);
        Bs[(c4 + 1) * 40 + kk] = f2bf(v.y);
        Bs[(c4 + 2) * 40 + kk] = f2bf(v.z);
        Bs[(c4 + 3) * 40 + kk] = f2bf(v.w);
      }
    }
    __syncthreads();
    bf16x8 af[4], bfr[4];
#pragma unroll
    for (int mt = 0; mt < 4; ++mt)
      af[mt] = *reinterpret_cast<const bf16x8*>(&As[(wm + mt * 16 + lr) * 40 + lg * 8]);
#pragma unroll
    for (int nt = 0; nt < 4; ++nt)
      bfr[nt] = *reinterpret_cast<const bf16x8*>(&Bs[(wn + nt * 16 + lr) * 40 + lg * 8]);
#pragma unroll
    for (int mt = 0; mt < 4; ++mt)
#pragma unroll
      for (int nt = 0; nt < 4; ++nt)
        acc[mt][nt] = __builtin_amdgcn_mfma_f32_16x16x32_bf16(af[mt], bfr[nt],
                                                              acc[mt][nt], 0, 0, 0);
  }
  // epilogue: scatter to Q/K/Vt
#pragma unroll
  for (int mt = 0; mt < 4; ++mt)
#pragma unroll
    for (int nt = 0; nt < 4; ++nt)
#pragma unroll
      for (int r = 0; r < 4; ++r) {
        const int m = m_base + wm + mt * 16 + lg * 4 + r;
        const int c = n_base + wn + nt * 16 + lr;
        float v = acc[mt][nt][r];
        const int which = c / 768;
        const int cc = c - which * 768;
        const int h = cc >> 6, d = cc & 63;
        if (which == 0) {
          qw[((size_t)h * N_TOK + m) * 64 + d] = f2bf(v * 0.125f);
        } else if (which == 1) {
          kw[((size_t)h * N_TOK + m) * 64 + d] = f2bf(v);
        } else {
          vw[((size_t)h * 64 + d) * N_TOK + m] = f2bf(v);
        }
      }
}

// ---------------------------------------------------------------------------
// Flash attention v2: swapped QK^T (S^T = mfma(K, Q)), in-register softmax,
// packed P writes, NO K/V LDS staging (L2-resident direct fragment loads),
// NO barriers. 4 independent waves per block, 16 q-rows per wave.
// ---------------------------------------------------------------------------
__global__ __launch_bounds__(256) void attn_kernel(
    const unsigned short* __restrict__ qw, const unsigned short* __restrict__ kw,
    const unsigned short* __restrict__ vw, unsigned short* __restrict__ ow) {
  __shared__ unsigned short Ps[4 * 16 * 72];  // per-wave P tile [q=16][kv=64] pad->72
  const int t = threadIdx.x;
  const int lane = t & 63, wid = t >> 6;
  const int lr = lane & 15, lg = lane >> 4;
  const int h = blockIdx.y;
  const int q0 = blockIdx.x * 64 + wid * 16;

  // Q fragments (B-operand): col = lr = q-row, k = d = lg*8..+7 (+32)
  bf16x8 qf[2];
  {
    const unsigned short* qp = &qw[((size_t)h * N_TOK + q0 + lr) * 64 + lg * 8];
    qf[0] = *reinterpret_cast<const bf16x8*>(qp);
    qf[1] = *reinterpret_cast<const bf16x8*>(qp + 32);
  }

  f32x4 acc_o[4];
#pragma unroll
  for (int nt = 0; nt < 4; ++nt) acc_o[nt] = (f32x4){0.f, 0.f, 0.f, 0.f};
  float m_run = -1e30f, l_run = 0.f;  // state for q-row lr (duplicated over lg)

  const unsigned short* kbase = &kw[(size_t)h * N_TOK * 64];
  const unsigned short* vbase = &vw[(size_t)h * 64 * N_TOK];
  unsigned short* pw = &Ps[wid * 16 * 72];

  for (int kv = 0; kv < N_TOK; kv += 64) {
    // S^T = K Q^T : rows = kv (nt*16 + lg*4 + r), col = q = lr
    f32x4 s_acc[4];
#pragma unroll
    for (int nt = 0; nt < 4; ++nt) {
      const size_t krow = (size_t)(kv + nt * 16 + lr) * 64 + lg * 8;
      const bf16x8 kf0 = *reinterpret_cast<const bf16x8*>(&kbase[krow]);
      const bf16x8 kf1 = *reinterpret_cast<const bf16x8*>(&kbase[krow + 32]);
      f32x4 z = (f32x4){0.f, 0.f, 0.f, 0.f};
      z = __builtin_amdgcn_mfma_f32_16x16x32_bf16(kf0, qf[0], z, 0, 0, 0);
      s_acc[nt] = __builtin_amdgcn_mfma_f32_16x16x32_bf16(kf1, qf[1], z, 0, 0, 0);
    }

    // row max for q = lr: 16 in-register values + 2 shuffles across lg
    float pm = s_acc[0][0];
#pragma unroll
    for (int nt = 0; nt < 4; ++nt)
#pragma unroll
      for (int r = 0; r < 4; ++r) pm = fmaxf(pm, s_acc[nt][r]);
    pm = fmaxf(pm, __shfl_xor(pm, 16));
    pm = fmaxf(pm, __shfl_xor(pm, 32));
    const float mn = fmaxf(m_run, pm);
    const float al = __expf(m_run - mn);
    m_run = mn;

    // P = exp(S - m), row sum
    float p[4][4];
    float rs = 0.f;
#pragma unroll
    for (int nt = 0; nt < 4; ++nt)
#pragma unroll
      for (int r = 0; r < 4; ++r) {
        const float pv = __expf(s_acc[nt][r] - mn);
        p[nt][r] = pv;
        rs += pv;
      }
    rs += __shfl_xor(rs, 16);
    rs += __shfl_xor(rs, 32);
    l_run = l_run * al + rs;

    // packed P write: lane holds kv = nt*16 + lg*4 + {0..3} for q-row lr
#pragma unroll
    for (int nt = 0; nt < 4; ++nt) {
      const unsigned d0 = (unsigned)f2bf(p[nt][0]) | ((unsigned)f2bf(p[nt][1]) << 16);
      const unsigned d1 = (unsigned)f2bf(p[nt][2]) | ((unsigned)f2bf(p[nt][3]) << 16);
      uint2 pk; pk.x = d0; pk.y = d1;
      *reinterpret_cast<uint2*>(&pw[lr * 72 + nt * 16 + lg * 4]) = pk;
    }
    __threadfence_block();  // order P writes before P fragment reads (same wave)

    // rescale O: acc_o row index is q = lg*4 + r -> broadcast al from lane lg*4+r
    float alb[4];
#pragma unroll
    for (int r = 0; r < 4; ++r) alb[r] = __shfl(al, lg * 4 + r);
#pragma unroll
    for (int nt = 0; nt < 4; ++nt)
#pragma unroll
      for (int r = 0; r < 4; ++r) acc_o[nt][r] *= alb[r];

    // O += P V : A = P frag (row=q=lr, k=kv), B = V^T frag (col=d=lr, k=kv)
#pragma unroll
    for (int ks = 0; ks < 2; ++ks) {
      const bf16x8 pf =
          *reinterpret_cast<const bf16x8*>(&pw[lr * 72 + ks * 32 + lg * 8]);
#pragma unroll
      for (int nt = 0; nt < 4; ++nt) {
        const bf16x8 vf = *reinterpret_cast<const bf16x8*>(
            &vbase[(size_t)(nt * 16 + lr) * N_TOK + kv + ks * 32 + lg * 8]);
        acc_o[nt] = __builtin_amdgcn_mfma_f32_16x16x32_bf16(pf, vf, acc_o[nt], 0, 0, 0);
      }
    }
  }

  // normalize + store O (bf16, [N][C] layout). inv for q-row lg*4+r via shfl.
  const float invl = 1.0f / l_run;  // for q = lr
  float invb[4];
#pragma unroll
  for (int r = 0; r < 4; ++r) invb[r] = __shfl(invl, lg * 4 + r);
  const int qrow0 = q0 + lg * 4;
#pragma unroll
  for (int nt = 0; nt < 4; ++nt)
#pragma unroll
    for (int r = 0; r < 4; ++r)
      ow[(size_t)(qrow0 + r) * C_DIM + h * 64 + nt * 16 + lr] =
          f2bf(acc_o[nt][r] * invb[r]);
}

// ---------------------------------------------------------------------------
// GEMM2: out = O @ w_proj + b_proj   (M=4096, K=768, N=768), f32 out
// ---------------------------------------------------------------------------
__global__ __launch_bounds__(256) void gemm_proj(
    const unsigned short* __restrict__ ob, const float* __restrict__ w,
    const float* __restrict__ bias, float* __restrict__ out) {
  __shared__ unsigned short As[128 * 40];
  __shared__ unsigned short Bs[128 * 40];
  const int t = threadIdx.x;
  const int lane = t & 63, wid = t >> 6;
  const int lr = lane & 15, lg = lane >> 4;
  const int m_base = blockIdx.y * 128, n_base = blockIdx.x * 128;
  const int wm = (wid >> 1) * 64, wn = (wid & 1) * 64;

  f32x4 acc[4][4];
#pragma unroll
  for (int mt = 0; mt < 4; ++mt)
#pragma unroll
    for (int nt = 0; nt < 4; ++nt) acc[mt][nt] = (f32x4){0.f, 0.f, 0.f, 0.f};

  for (int kt = 0; kt < 24; ++kt) {
    const int k0 = kt * 32;
    __syncthreads();
    // stage A: bf16 copy 128x32
#pragma unroll
    for (int rr = 0; rr < 2; ++rr) {
      const int s = t + rr * 256;
      const int row = s >> 2, sc = (s & 3) * 8;
      *reinterpret_cast<bf16x8*>(&As[row * 40 + sc]) =
          *reinterpret_cast<const bf16x8*>(&ob[(size_t)(m_base + row) * 768 + k0 + sc]);
    }
    // stage B transposed: 32x128 f32 -> bf16
    {
      const int kk0 = t >> 5, c4 = (t & 31) * 4;
#pragma unroll
      for (int rr = 0; rr < 4; ++rr) {
        const int kk = rr * 8 + kk0;
        const float4 v = *reinterpret_cast<const float4*>(
            &w[(size_t)(k0 + kk) * 768 + n_base + c4]);
        Bs[(c4 + 0) * 40 + kk] = f2bf(v.x);
        Bs[(c4 + 1) * 40 + kk] = f2bf(v.y);
        Bs[(c4 + 2) * 40 + kk] = f2bf(v.z);
        Bs[(c4 + 3) * 40 + kk] = f2bf(v.w);
      }
    }
    __syncthreads();
    bf16x8 af[4], bfr[4];
#pragma unroll
    for (int mt = 0; mt < 4; ++mt)
      af[mt] = *reinterpret_cast<const bf16x8*>(&As[(wm + mt * 16 + lr) * 40 + lg * 8]);
#pragma unroll
    for (int nt = 0; nt < 4; ++nt)
      bfr[nt] = *reinterpret_cast<const bf16x8*>(&Bs[(wn + nt * 16 + lr) * 40 + lg * 8]);
#pragma unroll
    for (int mt = 0; mt < 4; ++mt)
#pragma unroll
      for (int nt = 0; nt < 4; ++nt)
        acc[mt][nt] = __builtin_amdgcn_mfma_f32_16x16x32_bf16(af[mt], bfr[nt],
                                                              acc[mt][nt], 0, 0, 0);
  }
  // epilogue: f32 store + bias
#pragma unroll
  for (int nt = 0; nt < 4; ++nt) {
    const int n = n_base + wn + nt * 16 + lr;
    const float bv = bias[n];
#pragma unroll
    for (int mt = 0; mt < 4; ++mt)
#pragma unroll
      for (int r = 0; r < 4; ++r) {
        const int m = m_base + wm + mt * 16 + lg * 4 + r;
        out[(size_t)m * 768 + n] = acc[mt][nt][r] + bv;
      }
  }
}

extern "C" void kernel_launch(void* const* d_in, const int* in_sizes, int n_in,
                              void* d_out, int out_size, void* d_ws, size_t ws_size,
                              hipStream_t stream) {
  (void)in_sizes; (void)n_in; (void)out_size; (void)ws_size;
  const float* x = (const float*)d_in[0];
  const float* w_qkv = (const float*)d_in[1];
  const float* w_proj = (const float*)d_in[2];
  const float* b_proj = (const float*)d_in[3];
  float* out = (float*)d_out;

  unsigned short* qw = (unsigned short*)d_ws;
  unsigned short* kw = qw + (size_t)H_NUM * N_TOK * 64;
  unsigned short* vw = kw + (size_t)H_NUM * N_TOK * 64;
  unsigned short* ow = vw + (size_t)H_NUM * N_TOK * 64;

  gemm_qkv<<<dim3(QKV_N / 128, N_TOK / 128), 256, 0, stream>>>(x, w_qkv, qw, kw, vw);
  attn_kernel<<<dim3(N_TOK / 64, H_NUM), 256, 0, stream>>>(qw, kw, vw, ow);
  gemm_proj<<<dim3(C_DIM / 128, N_TOK / 128), 256, 0, stream>>>(ow, w_proj, b_proj, out);
}

// Round 3
// 287.084 us; speedup vs baseline: 1.6937x; 1.6937x over previous
//
#include <hip/hip_runtime.h>

#define N_TOK 4096
#define C_DIM 768
#define H_NUM 12
#define QKV_N 2304

typedef __attribute__((ext_vector_type(8))) short bf16x8;
typedef __attribute__((ext_vector_type(4))) float f32x4;

static __device__ __forceinline__ unsigned short f2bf(float f) {
  unsigned u = __builtin_bit_cast(unsigned, f);
  u += 0x7FFF + ((u >> 16) & 1);   // RNE
  return (unsigned short)(u >> 16);
}

// ---------------------------------------------------------------------------
// GEMM1: qkv = x @ w_qkv   (M=4096, K=768, N=2304), f32 in -> bf16 scatter out
// Q pre-scaled by 0.125; V stored transposed [H][64][N].
// ---------------------------------------------------------------------------
__global__ __launch_bounds__(256) void gemm_qkv(
    const float* __restrict__ x, const float* __restrict__ w,
    unsigned short* __restrict__ qw, unsigned short* __restrict__ kw,
    unsigned short* __restrict__ vw) {
  __shared__ unsigned short As[128 * 40];   // [m][k] pad 32->40
  __shared__ unsigned short Bs[128 * 40];   // [n][k] (transposed tile)
  const int t = threadIdx.x;
  const int lane = t & 63, wid = t >> 6;
  const int lr = lane & 15, lg = lane >> 4;
  const int m_base = blockIdx.y * 128, n_base = blockIdx.x * 128;
  const int wm = (wid >> 1) * 64, wn = (wid & 1) * 64;

  f32x4 acc[4][4];
#pragma unroll
  for (int mt = 0; mt < 4; ++mt)
#pragma unroll
    for (int nt = 0; nt < 4; ++nt) acc[mt][nt] = (f32x4){0.f, 0.f, 0.f, 0.f};

  for (int kt = 0; kt < 24; ++kt) {
    const int k0 = kt * 32;
    __syncthreads();
    // stage A: 128x32 f32 -> bf16
    {
      const int row = t >> 3, c4 = (t & 7) * 4;
#pragma unroll
      for (int rr = 0; rr < 4; ++rr) {
        const int r2 = rr * 32 + row;
        const float4 v = *reinterpret_cast<const float4*>(
            &x[(size_t)(m_base + r2) * 768 + k0 + c4]);
        unsigned short* d = &As[r2 * 40 + c4];
        d[0] = f2bf(v.x); d[1] = f2bf(v.y); d[2] = f2bf(v.z); d[3] = f2bf(v.w);
      }
    }
    // stage B transposed: 32x128 f32 -> bf16 [n][k]
    {
      const int kk0 = t >> 5, c4 = (t & 31) * 4;
#pragma unroll
      for (int rr = 0; rr < 4; ++rr) {
        const int kk = rr * 8 + kk0;
        const float4 v = *reinterpret_cast<const float4*>(
            &w[(size_t)(k0 + kk) * QKV_N + n_base + c4]);
        Bs[(c4 + 0) * 40 + kk] = f2bf(v.x);
        Bs[(c4 + 1) * 40 + kk] = f2bf(v.y);
        Bs[(c4 + 2) * 40 + kk] = f2bf(v.z);
        Bs[(c4 + 3) * 40 + kk] = f2bf(v.w);
      }
    }
    __syncthreads();
    bf16x8 af[4], bfr[4];
#pragma unroll
    for (int mt = 0; mt < 4; ++mt)
      af[mt] = *reinterpret_cast<const bf16x8*>(&As[(wm + mt * 16 + lr) * 40 + lg * 8]);
#pragma unroll
    for (int nt = 0; nt < 4; ++nt)
      bfr[nt] = *reinterpret_cast<const bf16x8*>(&Bs[(wn + nt * 16 + lr) * 40 + lg * 8]);
#pragma unroll
    for (int mt = 0; mt < 4; ++mt)
#pragma unroll
      for (int nt = 0; nt < 4; ++nt)
        acc[mt][nt] = __builtin_amdgcn_mfma_f32_16x16x32_bf16(af[mt], bfr[nt],
                                                              acc[mt][nt], 0, 0, 0);
  }
  // epilogue: scatter to Q/K/Vt
#pragma unroll
  for (int mt = 0; mt < 4; ++mt)
#pragma unroll
    for (int nt = 0; nt < 4; ++nt)
#pragma unroll
      for (int r = 0; r < 4; ++r) {
        const int m = m_base + wm + mt * 16 + lg * 4 + r;
        const int c = n_base + wn + nt * 16 + lr;
        float v = acc[mt][nt][r];
        const int which = c / 768;
        const int cc = c - which * 768;
        const int h = cc >> 6, d = cc & 63;
        if (which == 0) {
          qw[((size_t)h * N_TOK + m) * 64 + d] = f2bf(v * 0.125f);
        } else if (which == 1) {
          kw[((size_t)h * N_TOK + m) * 64 + d] = f2bf(v);
        } else {
          vw[((size_t)h * 64 + d) * N_TOK + m] = f2bf(v);
        }
      }
}

// ---------------------------------------------------------------------------
// Flash attention v3: LDS-staged K/V (shared by 4 waves) + swapped QK^T
// (S^T = mfma(K, Q)) in-register softmax + packed P writes. KV tile = 128.
// 4 waves x 16 q-rows per block.
// ---------------------------------------------------------------------------
__global__ __launch_bounds__(256) void attn_kernel(
    const unsigned short* __restrict__ qw, const unsigned short* __restrict__ kw,
    const unsigned short* __restrict__ vw, unsigned short* __restrict__ ow) {
  __shared__ unsigned short Ks[128 * 72];      // [kv][d]   pad 64->72   (18432 B)
  __shared__ unsigned short Vs[64 * 136];      // [d][kv]   pad 128->136 (17408 B)
  __shared__ unsigned short Ps[4 * 16 * 136];  // per-wave [q=16][kv=128] (17408 B)
  const int t = threadIdx.x;
  const int lane = t & 63, wid = t >> 6;
  const int lr = lane & 15, lg = lane >> 4;
  const int h = blockIdx.y;
  const int q0 = blockIdx.x * 64 + wid * 16;

  // Q fragments (B-operand): col = lr = q-row, k = d = lg*8..+7 (+32)
  bf16x8 qf[2];
  {
    const unsigned short* qp = &qw[((size_t)h * N_TOK + q0 + lr) * 64 + lg * 8];
    qf[0] = *reinterpret_cast<const bf16x8*>(qp);
    qf[1] = *reinterpret_cast<const bf16x8*>(qp + 32);
  }

  f32x4 acc_o[4];
#pragma unroll
  for (int nt = 0; nt < 4; ++nt) acc_o[nt] = (f32x4){0.f, 0.f, 0.f, 0.f};
  float m_run = -1e30f, l_run = 0.f;  // state for q-row lr (duplicated over lg)

  const unsigned short* kbase = &kw[(size_t)h * N_TOK * 64];
  const unsigned short* vbase = &vw[(size_t)h * 64 * N_TOK];
  unsigned short* pw = &Ps[wid * 16 * 136];

  for (int kv = 0; kv < N_TOK; kv += 128) {
    __syncthreads();
    // stage K [128][64]
#pragma unroll
    for (int rr = 0; rr < 4; ++rr) {
      const int s = t + rr * 256;
      const int row = s >> 3, seg = (s & 7) * 8;
      *reinterpret_cast<bf16x8*>(&Ks[row * 72 + seg]) =
          *reinterpret_cast<const bf16x8*>(&kbase[(size_t)(kv + row) * 64 + seg]);
    }
    // stage Vt [64][128]
#pragma unroll
    for (int rr = 0; rr < 4; ++rr) {
      const int s = t + rr * 256;
      const int row = s >> 4, seg = (s & 15) * 8;
      *reinterpret_cast<bf16x8*>(&Vs[row * 136 + seg]) =
          *reinterpret_cast<const bf16x8*>(&vbase[(size_t)row * N_TOK + kv + seg]);
    }
    __syncthreads();

    // S^T = K Q^T : rows = kv (nt*16 + lg*4 + r), col = q = lr
    f32x4 s_acc[8];
#pragma unroll
    for (int nt = 0; nt < 8; ++nt) {
      const bf16x8 kf0 =
          *reinterpret_cast<const bf16x8*>(&Ks[(nt * 16 + lr) * 72 + lg * 8]);
      const bf16x8 kf1 =
          *reinterpret_cast<const bf16x8*>(&Ks[(nt * 16 + lr) * 72 + 32 + lg * 8]);
      f32x4 z = (f32x4){0.f, 0.f, 0.f, 0.f};
      z = __builtin_amdgcn_mfma_f32_16x16x32_bf16(kf0, qf[0], z, 0, 0, 0);
      s_acc[nt] = __builtin_amdgcn_mfma_f32_16x16x32_bf16(kf1, qf[1], z, 0, 0, 0);
    }

    // row max for q = lr: 32 in-register values + 2 shuffles across lg
    float pm = s_acc[0][0];
#pragma unroll
    for (int nt = 0; nt < 8; ++nt)
#pragma unroll
      for (int r = 0; r < 4; ++r) pm = fmaxf(pm, s_acc[nt][r]);
    pm = fmaxf(pm, __shfl_xor(pm, 16));
    pm = fmaxf(pm, __shfl_xor(pm, 32));
    const float mn = fmaxf(m_run, pm);
    const float al = __expf(m_run - mn);
    m_run = mn;

    // P = exp(S - m) in place, row sum
    float rs = 0.f;
#pragma unroll
    for (int nt = 0; nt < 8; ++nt)
#pragma unroll
      for (int r = 0; r < 4; ++r) {
        const float pv = __expf(s_acc[nt][r] - mn);
        s_acc[nt][r] = pv;
        rs += pv;
      }
    rs += __shfl_xor(rs, 16);
    rs += __shfl_xor(rs, 32);
    l_run = l_run * al + rs;

    // packed P write: lane holds kv = nt*16 + lg*4 + {0..3} for q-row lr
#pragma unroll
    for (int nt = 0; nt < 8; ++nt) {
      uint2 pk;
      pk.x = (unsigned)f2bf(s_acc[nt][0]) | ((unsigned)f2bf(s_acc[nt][1]) << 16);
      pk.y = (unsigned)f2bf(s_acc[nt][2]) | ((unsigned)f2bf(s_acc[nt][3]) << 16);
      *reinterpret_cast<uint2*>(&pw[lr * 136 + nt * 16 + lg * 4]) = pk;
    }
    __threadfence_block();  // order P writes before same-wave P fragment reads

    // rescale O: acc_o row index is q = lg*4 + r -> broadcast al from lane lg*4+r
    float alb[4];
#pragma unroll
    for (int r = 0; r < 4; ++r) alb[r] = __shfl(al, lg * 4 + r);
#pragma unroll
    for (int nt = 0; nt < 4; ++nt)
#pragma unroll
      for (int r = 0; r < 4; ++r) acc_o[nt][r] *= alb[r];

    // O += P V : A = P frag (row=q=lr, k=kv), B = V^T frag (col=d=lr, k=kv)
#pragma unroll
    for (int ks = 0; ks < 4; ++ks) {
      const bf16x8 pf =
          *reinterpret_cast<const bf16x8*>(&pw[lr * 136 + ks * 32 + lg * 8]);
#pragma unroll
      for (int nt = 0; nt < 4; ++nt) {
        const bf16x8 vf = *reinterpret_cast<const bf16x8*>(
            &Vs[(nt * 16 + lr) * 136 + ks * 32 + lg * 8]);
        acc_o[nt] = __builtin_amdgcn_mfma_f32_16x16x32_bf16(pf, vf, acc_o[nt], 0, 0, 0);
      }
    }
  }

  // normalize + store O (bf16, [N][C] layout). inv for q-row lg*4+r via shfl.
  const float invl = 1.0f / l_run;  // for q = lr
  float invb[4];
#pragma unroll
  for (int r = 0; r < 4; ++r) invb[r] = __shfl(invl, lg * 4 + r);
  const int qrow0 = q0 + lg * 4;
#pragma unroll
  for (int nt = 0; nt < 4; ++nt)
#pragma unroll
    for (int r = 0; r < 4; ++r)
      ow[(size_t)(qrow0 + r) * C_DIM + h * 64 + nt * 16 + lr] =
          f2bf(acc_o[nt][r] * invb[r]);
}

// ---------------------------------------------------------------------------
// GEMM2: out = O @ w_proj + b_proj   (M=4096, K=768, N=768), f32 out
// ---------------------------------------------------------------------------
__global__ __launch_bounds__(256) void gemm_proj(
    const unsigned short* __restrict__ ob, const float* __restrict__ w,
    const float* __restrict__ bias, float* __restrict__ out) {
  __shared__ unsigned short As[128 * 40];
  __shared__ unsigned short Bs[128 * 40];
  const int t = threadIdx.x;
  const int lane = t & 63, wid = t >> 6;
  const int lr = lane & 15, lg = lane >> 4;
  const int m_base = blockIdx.y * 128, n_base = blockIdx.x * 128;
  const int wm = (wid >> 1) * 64, wn = (wid & 1) * 64;

  f32x4 acc[4][4];
#pragma unroll
  for (int mt = 0; mt < 4; ++mt)
#pragma unroll
    for (int nt = 0; nt < 4; ++nt) acc[mt][nt] = (f32x4){0.f, 0.f, 0.f, 0.f};

  for (int kt = 0; kt < 24; ++kt) {
    const int k0 = kt * 32;
    __syncthreads();
    // stage A: bf16 copy 128x32
#pragma unroll
    for (int rr = 0; rr < 2; ++rr) {
      const int s = t + rr * 256;
      const int row = s >> 2, sc = (s & 3) * 8;
      *reinterpret_cast<bf16x8*>(&As[row * 40 + sc]) =
          *reinterpret_cast<const bf16x8*>(&ob[(size_t)(m_base + row) * 768 + k0 + sc]);
    }
    // stage B transposed: 32x128 f32 -> bf16
    {
      const int kk0 = t >> 5, c4 = (t & 31) * 4;
#pragma unroll
      for (int rr = 0; rr < 4; ++rr) {
        const int kk = rr * 8 + kk0;
        const float4 v = *reinterpret_cast<const float4*>(
            &w[(size_t)(k0 + kk) * 768 + n_base + c4]);
        Bs[(c4 + 0) * 40 + kk] = f2bf(v.x);
        Bs[(c4 + 1) * 40 + kk] = f2bf(v.y);
        Bs[(c4 + 2) * 40 + kk] = f2bf(v.z);
        Bs[(c4 + 3) * 40 + kk] = f2bf(v.w);
      }
    }
    __syncthreads();
    bf16x8 af[4], bfr[4];
#pragma unroll
    for (int mt = 0; mt < 4; ++mt)
      af[mt] = *reinterpret_cast<const bf16x8*>(&As[(wm + mt * 16 + lr) * 40 + lg * 8]);
#pragma unroll
    for (int nt = 0; nt < 4; ++nt)
      bfr[nt] = *reinterpret_cast<const bf16x8*>(&Bs[(wn + nt * 16 + lr) * 40 + lg * 8]);
#pragma unroll
    for (int mt = 0; mt < 4; ++mt)
#pragma unroll
      for (int nt = 0; nt < 4; ++nt)
        acc[mt][nt] = __builtin_amdgcn_mfma_f32_16x16x32_bf16(af[mt], bfr[nt],
                                                              acc[mt][nt], 0, 0, 0);
  }
  // epilogue: f32 store + bias
#pragma unroll
  for (int nt = 0; nt < 4; ++nt) {
    const int n = n_base + wn + nt * 16 + lr;
    const float bv = bias[n];
#pragma unroll
    for (int mt = 0; mt < 4; ++mt)
#pragma unroll
      for (int r = 0; r < 4; ++r) {
        const int m = m_base + wm + mt * 16 + lg * 4 + r;
        out[(size_t)m * 768 + n] = acc[mt][nt][r] + bv;
      }
  }
}

extern "C" void kernel_launch(void* const* d_in, const int* in_sizes, int n_in,
                              void* d_out, int out_size, void* d_ws, size_t ws_size,
                              hipStream_t stream) {
  (void)in_sizes; (void)n_in; (void)out_size; (void)ws_size;
  const float* x = (const float*)d_in[0];
  const float* w_qkv = (const float*)d_in[1];
  const float* w_proj = (const float*)d_in[2];
  const float* b_proj = (const float*)d_in[3];
  float* out = (float*)d_out;

  unsigned short* qw = (unsigned short*)d_ws;
  unsigned short* kw = qw + (size_t)H_NUM * N_TOK * 64;
  unsigned short* vw = kw + (size_t)H_NUM * N_TOK * 64;
  unsigned short* ow = vw + (size_t)H_NUM * N_TOK * 64;

  gemm_qkv<<<dim3(QKV_N / 128, N_TOK / 128), 256, 0, stream>>>(x, w_qkv, qw, kw, vw);
  attn_kernel<<<dim3(N_TOK / 64, H_NUM), 256, 0, stream>>>(qw, kw, vw, ow);
  gemm_proj<<<dim3(C_DIM / 128, N_TOK / 128), 256, 0, stream>>>(ow, w_proj, b_proj, out);
}

// Round 4
// 249.797 us; speedup vs baseline: 1.9465x; 1.1493x over previous
//
#include <hip/hip_runtime.h>

#define N_TOK 4096
#define C_DIM 768
#define H_NUM 12
#define QKV_N 2304

typedef __attribute__((ext_vector_type(8))) short bf16x8;
typedef __attribute__((ext_vector_type(4))) float f32x4;
typedef __attribute__((ext_vector_type(16))) float f32x16;
typedef __attribute__((ext_vector_type(4))) unsigned int u32x4;

static __device__ __forceinline__ unsigned short f2bf(float f) {
  unsigned u = __builtin_bit_cast(unsigned, f);
  u += 0x7FFF + ((u >> 16) & 1);   // RNE
  return (unsigned short)(u >> 16);
}

// ---------------------------------------------------------------------------
// GEMM1: qkv = x @ w_qkv   (M=4096, K=768, N=2304), f32 in -> bf16 scatter out
// Q pre-scaled by 0.125; V stored transposed [H][64][N].
// ---------------------------------------------------------------------------
__global__ __launch_bounds__(256) void gemm_qkv(
    const float* __restrict__ x, const float* __restrict__ w,
    unsigned short* __restrict__ qw, unsigned short* __restrict__ kw,
    unsigned short* __restrict__ vw) {
  __shared__ unsigned short As[128 * 40];   // [m][k] pad 32->40
  __shared__ unsigned short Bs[128 * 40];   // [n][k] (transposed tile)
  const int t = threadIdx.x;
  const int lane = t & 63, wid = t >> 6;
  const int lr = lane & 15, lg = lane >> 4;
  const int m_base = blockIdx.y * 128, n_base = blockIdx.x * 128;
  const int wm = (wid >> 1) * 64, wn = (wid & 1) * 64;

  f32x4 acc[4][4];
#pragma unroll
  for (int mt = 0; mt < 4; ++mt)
#pragma unroll
    for (int nt = 0; nt < 4; ++nt) acc[mt][nt] = (f32x4){0.f, 0.f, 0.f, 0.f};

  for (int kt = 0; kt < 24; ++kt) {
    const int k0 = kt * 32;
    __syncthreads();
    // stage A: 128x32 f32 -> bf16
    {
      const int row = t >> 3, c4 = (t & 7) * 4;
#pragma unroll
      for (int rr = 0; rr < 4; ++rr) {
        const int r2 = rr * 32 + row;
        const float4 v = *reinterpret_cast<const float4*>(
            &x[(size_t)(m_base + r2) * 768 + k0 + c4]);
        unsigned short* d = &As[r2 * 40 + c4];
        d[0] = f2bf(v.x); d[1] = f2bf(v.y); d[2] = f2bf(v.z); d[3] = f2bf(v.w);
      }
    }
    // stage B transposed: 32x128 f32 -> bf16 [n][k]
    {
      const int kk0 = t >> 5, c4 = (t & 31) * 4;
#pragma unroll
      for (int rr = 0; rr < 4; ++rr) {
        const int kk = rr * 8 + kk0;
        const float4 v = *reinterpret_cast<const float4*>(
            &w[(size_t)(k0 + kk) * QKV_N + n_base + c4]);
        Bs[(c4 + 0) * 40 + kk] = f2bf(v.x);
        Bs[(c4 + 1) * 40 + kk] = f2bf(v.y);
        Bs[(c4 + 2) * 40 + kk] = f2bf(v.z);
        Bs[(c4 + 3) * 40 + kk] = f2bf(v.w);
      }
    }
    __syncthreads();
    bf16x8 af[4], bfr[4];
#pragma unroll
    for (int mt = 0; mt < 4; ++mt)
      af[mt] = *reinterpret_cast<const bf16x8*>(&As[(wm + mt * 16 + lr) * 40 + lg * 8]);
#pragma unroll
    for (int nt = 0; nt < 4; ++nt)
      bfr[nt] = *reinterpret_cast<const bf16x8*>(&Bs[(wn + nt * 16 + lr) * 40 + lg * 8]);
#pragma unroll
    for (int mt = 0; mt < 4; ++mt)
#pragma unroll
      for (int nt = 0; nt < 4; ++nt)
        acc[mt][nt] = __builtin_amdgcn_mfma_f32_16x16x32_bf16(af[mt], bfr[nt],
                                                              acc[mt][nt], 0, 0, 0);
  }
  // epilogue: scatter to Q/K/Vt
#pragma unroll
  for (int mt = 0; mt < 4; ++mt)
#pragma unroll
    for (int nt = 0; nt < 4; ++nt)
#pragma unroll
      for (int r = 0; r < 4; ++r) {
        const int m = m_base + wm + mt * 16 + lg * 4 + r;
        const int c = n_base + wn + nt * 16 + lr;
        float v = acc[mt][nt][r];
        const int which = c / 768;
        const int cc = c - which * 768;
        const int h = cc >> 6, d = cc & 63;
        if (which == 0) {
          qw[((size_t)h * N_TOK + m) * 64 + d] = f2bf(v * 0.125f);
        } else if (which == 1) {
          kw[((size_t)h * N_TOK + m) * 64 + d] = f2bf(v);
        } else {
          vw[((size_t)h * 64 + d) * N_TOK + m] = f2bf(v);
        }
      }
}

// ---------------------------------------------------------------------------
// Flash attention v4: 32x32x16 MFMA, swapped QK^T (S^T = mfma(K, Q)),
// fully in-register P via v_cvt_pk_bf16_f32 + v_permlane32_swap_b32 (T12),
// defer-max rescale THR=8 (T13), async-stage split prefetch (T14).
// 2 waves x 32 q-rows = 64 q/block, KVBLK=64, grid 64x12 = 768 blocks.
// ---------------------------------------------------------------------------
__global__ __launch_bounds__(128) void attn_kernel(
    const unsigned short* __restrict__ qw, const unsigned short* __restrict__ kw,
    const unsigned short* __restrict__ vw, unsigned short* __restrict__ ow) {
  __shared__ unsigned short Ks[64 * 72];   // [kv][d] pad 64->72 (9216 B)
  __shared__ unsigned short Vs[64 * 72];   // [d][kv] pad 64->72 (9216 B)
  const int t = threadIdx.x;               // 0..127
  const int lane = t & 63;
  const int q31 = lane & 31;
  const int hi = lane >> 5;
  const int h = blockIdx.y;
  const int q0 = blockIdx.x * 64 + (t >> 6) * 32;

  const unsigned short* kbase = &kw[(size_t)h * N_TOK * 64];
  const unsigned short* vbase = &vw[(size_t)h * 64 * N_TOK];

  // Q fragments (B-operand of 32x32x16): col = q31, k = d = ks*16 + hi*8 + j
  bf16x8 qf[4];
#pragma unroll
  for (int ks = 0; ks < 4; ++ks)
    qf[ks] = *reinterpret_cast<const bf16x8*>(
        &qw[((size_t)h * N_TOK + q0 + q31) * 64 + ks * 16 + hi * 8]);

  f32x16 acc0, acc1;   // O accumulators: col = d (q31 | 32+q31), row = crow(r,hi)=q
#pragma unroll
  for (int r = 0; r < 16; ++r) { acc0[r] = 0.f; acc1[r] = 0.f; }
  float m_run = -1e30f, l_run = 0.f;   // per-q state, q = q31 (dup over hi)

  // staging mapping: s = t + i*128, row = s>>3, seg = (s&7)*8
  const int srow = t >> 3;
  const int sseg = (t & 7) * 8;

  bf16x8 kst[4], vst[4];
#pragma unroll
  for (int i = 0; i < 4; ++i) {
    const int row = srow + i * 16;
    kst[i] = *reinterpret_cast<const bf16x8*>(&kbase[(size_t)row * 64 + sseg]);
    vst[i] = *reinterpret_cast<const bf16x8*>(&vbase[(size_t)row * N_TOK + sseg]);
  }

  for (int kv = 0; kv < N_TOK; kv += 64) {
    __syncthreads();   // previous tile fully consumed
#pragma unroll
    for (int i = 0; i < 4; ++i) {
      const int row = srow + i * 16;
      *reinterpret_cast<bf16x8*>(&Ks[row * 72 + sseg]) = kst[i];
      *reinterpret_cast<bf16x8*>(&Vs[row * 72 + sseg]) = vst[i];
    }
    __syncthreads();
    // T14: issue next tile's global loads now; latency hides under compute
    const int kvn = (kv + 64 < N_TOK) ? kv + 64 : 0;
#pragma unroll
    for (int i = 0; i < 4; ++i) {
      const int row = srow + i * 16;
      kst[i] = *reinterpret_cast<const bf16x8*>(&kbase[(size_t)(kvn + row) * 64 + sseg]);
      vst[i] = *reinterpret_cast<const bf16x8*>(&vbase[(size_t)row * N_TOK + kvn + sseg]);
    }

#pragma unroll
    for (int ct = 0; ct < 2; ++ct) {
      // S^T = K Q^T : rows = kv = crow(r,hi) + ct*32, col = q = q31
      f32x16 s;
#pragma unroll
      for (int r = 0; r < 16; ++r) s[r] = 0.f;
#pragma unroll
      for (int ks = 0; ks < 4; ++ks) {
        const bf16x8 kf = *reinterpret_cast<const bf16x8*>(
            &Ks[(ct * 32 + q31) * 72 + ks * 16 + hi * 8]);
        s = __builtin_amdgcn_mfma_f32_32x32x16_bf16(kf, qf[ks], s, 0, 0, 0);
      }
      // tile max for q: 15 in-lane + 1 cross-half shuffle
      float pm = s[0];
#pragma unroll
      for (int r = 1; r < 16; ++r) pm = fmaxf(pm, s[r]);
      pm = fmaxf(pm, __shfl_xor(pm, 32));
      // T13 defer-max: only rescale when max grows past threshold
      if (!__all(pm <= m_run + 8.f)) {
        const float newm = fmaxf(m_run, pm);
        const float al = __expf(m_run - newm);
        m_run = newm;
        l_run *= al;
#pragma unroll
        for (int r = 0; r < 16; ++r) {
          const float a = __shfl(al, (r & 3) + 8 * (r >> 2) + 4 * hi);
          acc0[r] *= a; acc1[r] *= a;
        }
      }
      float p[16];
      float rs = 0.f;
#pragma unroll
      for (int r = 0; r < 16; ++r) { p[r] = __expf(s[r] - m_run); rs += p[r]; }
      rs += __shfl_xor(rs, 32);
      l_run += rs;

      // T12: pack P to bf16 pairs, permlane32_swap to form PV A-fragments.
      // dw[m] = pack(p[2m], p[2m+1]); swap(dw0,dw2),(dw1,dw3) -> frag ks=0;
      // swap(dw4,dw6),(dw5,dw7) -> frag ks=1.
      unsigned dw[8];
#pragma unroll
      for (int m2 = 0; m2 < 8; ++m2)
        asm("v_cvt_pk_bf16_f32 %0, %1, %2"
            : "=v"(dw[m2]) : "v"(p[2 * m2]), "v"(p[2 * m2 + 1]));
      asm("v_permlane32_swap_b32 %0, %1" : "+v"(dw[0]), "+v"(dw[2]));
      asm("v_permlane32_swap_b32 %0, %1" : "+v"(dw[1]), "+v"(dw[3]));
      asm("v_permlane32_swap_b32 %0, %1" : "+v"(dw[4]), "+v"(dw[6]));
      asm("v_permlane32_swap_b32 %0, %1" : "+v"(dw[5]), "+v"(dw[7]));

#pragma unroll
      for (int ksl = 0; ksl < 2; ++ksl) {
        u32x4 u;
        u.x = dw[ksl * 4 + 0]; u.y = dw[ksl * 4 + 1];
        u.z = dw[ksl * 4 + 2]; u.w = dw[ksl * 4 + 3];
        const bf16x8 pa = __builtin_bit_cast(bf16x8, u);
        const int kg = ct * 2 + ksl;   // kv k-step within the 64-tile
        const bf16x8 vf0 = *reinterpret_cast<const bf16x8*>(
            &Vs[q31 * 72 + kg * 16 + hi * 8]);
        const bf16x8 vf1 = *reinterpret_cast<const bf16x8*>(
            &Vs[(32 + q31) * 72 + kg * 16 + hi * 8]);
        acc0 = __builtin_amdgcn_mfma_f32_32x32x16_bf16(pa, vf0, acc0, 0, 0, 0);
        acc1 = __builtin_amdgcn_mfma_f32_32x32x16_bf16(pa, vf1, acc1, 0, 0, 0);
      }
    }
  }

  // normalize + store O (bf16, [N][C]): lane writes rows q=crow(r,hi), cols d
  const float inv = 1.0f / l_run;
#pragma unroll
  for (int r = 0; r < 16; ++r) {
    const int crow = (r & 3) + 8 * (r >> 2) + 4 * hi;
    const float iv = __shfl(inv, crow);
    const size_t base = (size_t)(q0 + crow) * C_DIM + h * 64;
    ow[base + q31] = f2bf(acc0[r] * iv);
    ow[base + 32 + q31] = f2bf(acc1[r] * iv);
  }
}

// ---------------------------------------------------------------------------
// GEMM2: out = O @ w_proj + b_proj   (M=4096, K=768, N=768), f32 out
// ---------------------------------------------------------------------------
__global__ __launch_bounds__(256) void gemm_proj(
    const unsigned short* __restrict__ ob, const float* __restrict__ w,
    const float* __restrict__ bias, float* __restrict__ out) {
  __shared__ unsigned short As[128 * 40];
  __shared__ unsigned short Bs[128 * 40];
  const int t = threadIdx.x;
  const int lane = t & 63, wid = t >> 6;
  const int lr = lane & 15, lg = lane >> 4;
  const int m_base = blockIdx.y * 128, n_base = blockIdx.x * 128;
  const int wm = (wid >> 1) * 64, wn = (wid & 1) * 64;

  f32x4 acc[4][4];
#pragma unroll
  for (int mt = 0; mt < 4; ++mt)
#pragma unroll
    for (int nt = 0; nt < 4; ++nt) acc[mt][nt] = (f32x4){0.f, 0.f, 0.f, 0.f};

  for (int kt = 0; kt < 24; ++kt) {
    const int k0 = kt * 32;
    __syncthreads();
    // stage A: bf16 copy 128x32
#pragma unroll
    for (int rr = 0; rr < 2; ++rr) {
      const int s = t + rr * 256;
      const int row = s >> 2, sc = (s & 3) * 8;
      *reinterpret_cast<bf16x8*>(&As[row * 40 + sc]) =
          *reinterpret_cast<const bf16x8*>(&ob[(size_t)(m_base + row) * 768 + k0 + sc]);
    }
    // stage B transposed: 32x128 f32 -> bf16
    {
      const int kk0 = t >> 5, c4 = (t & 31) * 4;
#pragma unroll
      for (int rr = 0; rr < 4; ++rr) {
        const int kk = rr * 8 + kk0;
        const float4 v = *reinterpret_cast<const float4*>(
            &w[(size_t)(k0 + kk) * 768 + n_base + c4]);
        Bs[(c4 + 0) * 40 + kk] = f2bf(v.x);
        Bs[(c4 + 1) * 40 + kk] = f2bf(v.y);
        Bs[(c4 + 2) * 40 + kk] = f2bf(v.z);
        Bs[(c4 + 3) * 40 + kk] = f2bf(v.w);
      }
    }
    __syncthreads();
    bf16x8 af[4], bfr[4];
#pragma unroll
    for (int mt = 0; mt < 4; ++mt)
      af[mt] = *reinterpret_cast<const bf16x8*>(&As[(wm + mt * 16 + lr) * 40 + lg * 8]);
#pragma unroll
    for (int nt = 0; nt < 4; ++nt)
      bfr[nt] = *reinterpret_cast<const bf16x8*>(&Bs[(wn + nt * 16 + lr) * 40 + lg * 8]);
#pragma unroll
    for (int mt = 0; mt < 4; ++mt)
#pragma unroll
      for (int nt = 0; nt < 4; ++nt)
        acc[mt][nt] = __builtin_amdgcn_mfma_f32_16x16x32_bf16(af[mt], bfr[nt],
                                                              acc[mt][nt], 0, 0, 0);
  }
  // epilogue: f32 store + bias
#pragma unroll
  for (int nt = 0; nt < 4; ++nt) {
    const int n = n_base + wn + nt * 16 + lr;
    const float bv = bias[n];
#pragma unroll
    for (int mt = 0; mt < 4; ++mt)
#pragma unroll
      for (int r = 0; r < 4; ++r) {
        const int m = m_base + wm + mt * 16 + lg * 4 + r;
        out[(size_t)m * 768 + n] = acc[mt][nt][r] + bv;
      }
  }
}

extern "C" void kernel_launch(void* const* d_in, const int* in_sizes, int n_in,
                              void* d_out, int out_size, void* d_ws, size_t ws_size,
                              hipStream_t stream) {
  (void)in_sizes; (void)n_in; (void)out_size; (void)ws_size;
  const float* x = (const float*)d_in[0];
  const float* w_qkv = (const float*)d_in[1];
  const float* w_proj = (const float*)d_in[2];
  const float* b_proj = (const float*)d_in[3];
  float* out = (float*)d_out;

  unsigned short* qw = (unsigned short*)d_ws;
  unsigned short* kw = qw + (size_t)H_NUM * N_TOK * 64;
  unsigned short* vw = kw + (size_t)H_NUM * N_TOK * 64;
  unsigned short* ow = vw + (size_t)H_NUM * N_TOK * 64;

  gemm_qkv<<<dim3(QKV_N / 128, N_TOK / 128), 256, 0, stream>>>(x, w_qkv, qw, kw, vw);
  attn_kernel<<<dim3(N_TOK / 64, H_NUM), 128, 0, stream>>>(qw, kw, vw, ow);
  gemm_proj<<<dim3(C_DIM / 128, N_TOK / 128), 256, 0, stream>>>(ow, w_proj, b_proj, out);
}

// Round 5
// 176.443 us; speedup vs baseline: 2.7558x; 1.4157x over previous
//
#include <hip/hip_runtime.h>

#define N_TOK 4096
#define C_DIM 768
#define H_NUM 12
#define QKV_N 2304

typedef __attribute__((ext_vector_type(8))) short bf16x8;
typedef __attribute__((ext_vector_type(4))) float f32x4;
typedef __attribute__((ext_vector_type(16))) float f32x16;
typedef __attribute__((ext_vector_type(4))) unsigned int u32x4;

static __device__ __forceinline__ unsigned short f2bf(float f) {
  unsigned u = __builtin_bit_cast(unsigned, f);
  u += 0x7FFF + ((u >> 16) & 1);   // RNE
  return (unsigned short)(u >> 16);
}

#define GLOAD_LDS16(g, l)                                                     \
  __builtin_amdgcn_global_load_lds(                                           \
      (const __attribute__((address_space(1))) void*)(g),                     \
      (__attribute__((address_space(3))) void*)(l), 16, 0, 0)

// ---------------------------------------------------------------------------
// Prep 1: elementwise f32 -> bf16 (x -> xb)
// ---------------------------------------------------------------------------
__global__ __launch_bounds__(256) void conv_bf16(
    const float* __restrict__ in, unsigned short* __restrict__ out, int n8) {
  const int i = blockIdx.x * 256 + threadIdx.x;  // 8 elems per thread
  if (i >= n8) return;
  const float4 a = reinterpret_cast<const float4*>(in)[i * 2];
  const float4 b = reinterpret_cast<const float4*>(in)[i * 2 + 1];
  unsigned short tmp[8] = {f2bf(a.x), f2bf(a.y), f2bf(a.z), f2bf(a.w),
                           f2bf(b.x), f2bf(b.y), f2bf(b.z), f2bf(b.w)};
  reinterpret_cast<bf16x8*>(out)[i] = *reinterpret_cast<bf16x8*>(tmp);
}

// ---------------------------------------------------------------------------
// Prep 2: tiled transpose + convert. in f32 [K][N] -> out bf16 [N][K].
// 64x64 tile per 256-thread block.
// ---------------------------------------------------------------------------
__global__ __launch_bounds__(256) void transpose_cvt(
    const float* __restrict__ in, unsigned short* __restrict__ out,
    int K, int N) {
  __shared__ unsigned short T[64][65];
  const int t = threadIdx.x;
  const int k0 = blockIdx.y * 64, n0 = blockIdx.x * 64;
  {
    const int r = t >> 2, qd = t & 3;
#pragma unroll
    for (int i = 0; i < 4; ++i) {
      const int c = qd * 16 + i * 4;
      const float4 v = *reinterpret_cast<const float4*>(
          &in[(size_t)(k0 + r) * N + n0 + c]);
      T[r][c + 0] = f2bf(v.x); T[r][c + 1] = f2bf(v.y);
      T[r][c + 2] = f2bf(v.z); T[r][c + 3] = f2bf(v.w);
    }
  }
  __syncthreads();
#pragma unroll
  for (int i = 0; i < 2; ++i) {
    const int cid = t + i * 256;
    const int rn = cid >> 3, cx = cid & 7;
    unsigned short tmp[8];
#pragma unroll
    for (int j = 0; j < 8; ++j) tmp[j] = T[cx * 8 + j][rn];
    *reinterpret_cast<bf16x8*>(&out[(size_t)(n0 + rn) * K + k0 + cx * 8]) =
        *reinterpret_cast<bf16x8*>(tmp);
  }
}

// ---------------------------------------------------------------------------
// GEMM1 (m97 structure): qkv = xb @ wqkvT^T. A [4096][768] bf16,
// Bt [2304][768] bf16. 128x128 tile, BK=32, global_load_lds staging.
// Epilogue scatters Q (x0.125) / K / V^T.
// ---------------------------------------------------------------------------
__global__ __launch_bounds__(256) void gemm_qkv_bf16(
    const unsigned short* __restrict__ A, const unsigned short* __restrict__ Bt,
    unsigned short* __restrict__ qw, unsigned short* __restrict__ kw,
    unsigned short* __restrict__ vw) {
  __shared__ unsigned short As[128 * 32];
  __shared__ unsigned short Bs[128 * 32];
  const int t = threadIdx.x;
  const int lane = t & 63, wid = t >> 6;
  const int lr = lane & 15, lg = lane >> 4;
  const int m_base = blockIdx.y * 128, n_base = blockIdx.x * 128;
  const int wm = (wid >> 1) * 64, wn = (wid & 1) * 64;
  const int c_row = lane >> 2;         // row within 16-row chunk
  const int c_col = (lane & 3) * 8;    // shorts

  f32x4 acc[4][4];
#pragma unroll
  for (int mt = 0; mt < 4; ++mt)
#pragma unroll
    for (int nt = 0; nt < 4; ++nt) acc[mt][nt] = (f32x4){0.f, 0.f, 0.f, 0.f};

  for (int kt = 0; kt < 24; ++kt) {
    const int k0 = kt * 32;
    __syncthreads();
#pragma unroll
    for (int i = 0; i < 2; ++i) {
      const int ch = wid * 2 + i;
      GLOAD_LDS16(&A[(size_t)(m_base + ch * 16 + c_row) * 768 + k0 + c_col],
                  &As[ch * 512]);
      GLOAD_LDS16(&Bt[(size_t)(n_base + ch * 16 + c_row) * 768 + k0 + c_col],
                  &Bs[ch * 512]);
    }
    __syncthreads();
    bf16x8 af[4], bfr[4];
#pragma unroll
    for (int mt = 0; mt < 4; ++mt)
      af[mt] = *reinterpret_cast<const bf16x8*>(&As[(wm + mt * 16 + lr) * 32 + lg * 8]);
#pragma unroll
    for (int nt = 0; nt < 4; ++nt)
      bfr[nt] = *reinterpret_cast<const bf16x8*>(&Bs[(wn + nt * 16 + lr) * 32 + lg * 8]);
#pragma unroll
    for (int mt = 0; mt < 4; ++mt)
#pragma unroll
      for (int nt = 0; nt < 4; ++nt)
        acc[mt][nt] = __builtin_amdgcn_mfma_f32_16x16x32_bf16(af[mt], bfr[nt],
                                                              acc[mt][nt], 0, 0, 0);
  }
  // epilogue: scatter to Q/K/Vt (per-block column region is uniform)
#pragma unroll
  for (int mt = 0; mt < 4; ++mt)
#pragma unroll
    for (int nt = 0; nt < 4; ++nt)
#pragma unroll
      for (int r = 0; r < 4; ++r) {
        const int m = m_base + wm + mt * 16 + lg * 4 + r;
        const int c = n_base + wn + nt * 16 + lr;
        const float v = acc[mt][nt][r];
        const int which = c / 768;
        const int cc = c - which * 768;
        const int h = cc >> 6, d = cc & 63;
        if (which == 0) {
          qw[((size_t)h * N_TOK + m) * 64 + d] = f2bf(v * 0.125f);
        } else if (which == 1) {
          kw[((size_t)h * N_TOK + m) * 64 + d] = f2bf(v);
        } else {
          vw[((size_t)h * 64 + d) * N_TOK + m] = f2bf(v);
        }
      }
}

// ---------------------------------------------------------------------------
// GEMM2 (m97 structure): out = ow @ wprojT^T + bias. f32 out.
// ---------------------------------------------------------------------------
__global__ __launch_bounds__(256) void gemm_proj_bf16(
    const unsigned short* __restrict__ A, const unsigned short* __restrict__ Bt,
    const float* __restrict__ bias, float* __restrict__ out) {
  __shared__ unsigned short As[128 * 32];
  __shared__ unsigned short Bs[128 * 32];
  const int t = threadIdx.x;
  const int lane = t & 63, wid = t >> 6;
  const int lr = lane & 15, lg = lane >> 4;
  const int m_base = blockIdx.y * 128, n_base = blockIdx.x * 128;
  const int wm = (wid >> 1) * 64, wn = (wid & 1) * 64;
  const int c_row = lane >> 2;
  const int c_col = (lane & 3) * 8;

  f32x4 acc[4][4];
#pragma unroll
  for (int mt = 0; mt < 4; ++mt)
#pragma unroll
    for (int nt = 0; nt < 4; ++nt) acc[mt][nt] = (f32x4){0.f, 0.f, 0.f, 0.f};

  for (int kt = 0; kt < 24; ++kt) {
    const int k0 = kt * 32;
    __syncthreads();
#pragma unroll
    for (int i = 0; i < 2; ++i) {
      const int ch = wid * 2 + i;
      GLOAD_LDS16(&A[(size_t)(m_base + ch * 16 + c_row) * 768 + k0 + c_col],
                  &As[ch * 512]);
      GLOAD_LDS16(&Bt[(size_t)(n_base + ch * 16 + c_row) * 768 + k0 + c_col],
                  &Bs[ch * 512]);
    }
    __syncthreads();
    bf16x8 af[4], bfr[4];
#pragma unroll
    for (int mt = 0; mt < 4; ++mt)
      af[mt] = *reinterpret_cast<const bf16x8*>(&As[(wm + mt * 16 + lr) * 32 + lg * 8]);
#pragma unroll
    for (int nt = 0; nt < 4; ++nt)
      bfr[nt] = *reinterpret_cast<const bf16x8*>(&Bs[(wn + nt * 16 + lr) * 32 + lg * 8]);
#pragma unroll
    for (int mt = 0; mt < 4; ++mt)
#pragma unroll
      for (int nt = 0; nt < 4; ++nt)
        acc[mt][nt] = __builtin_amdgcn_mfma_f32_16x16x32_bf16(af[mt], bfr[nt],
                                                              acc[mt][nt], 0, 0, 0);
  }
#pragma unroll
  for (int nt = 0; nt < 4; ++nt) {
    const int n = n_base + wn + nt * 16 + lr;
    const float bv = bias[n];
#pragma unroll
    for (int mt = 0; mt < 4; ++mt)
#pragma unroll
      for (int r = 0; r < 4; ++r) {
        const int m = m_base + wm + mt * 16 + lg * 4 + r;
        out[(size_t)m * 768 + n] = acc[mt][nt][r] + bv;
      }
  }
}

// ---------------------------------------------------------------------------
// Flash attention v4 (unchanged from round 4): 32x32x16 MFMA, swapped QK^T,
// in-register P (cvt_pk + permlane32_swap), defer-max, prefetch staging.
// ---------------------------------------------------------------------------
__global__ __launch_bounds__(128) void attn_kernel(
    const unsigned short* __restrict__ qw, const unsigned short* __restrict__ kw,
    const unsigned short* __restrict__ vw, unsigned short* __restrict__ ow) {
  __shared__ unsigned short Ks[64 * 72];
  __shared__ unsigned short Vs[64 * 72];
  const int t = threadIdx.x;
  const int lane = t & 63;
  const int q31 = lane & 31;
  const int hi = lane >> 5;
  const int h = blockIdx.y;
  const int q0 = blockIdx.x * 64 + (t >> 6) * 32;

  const unsigned short* kbase = &kw[(size_t)h * N_TOK * 64];
  const unsigned short* vbase = &vw[(size_t)h * 64 * N_TOK];

  bf16x8 qf[4];
#pragma unroll
  for (int ks = 0; ks < 4; ++ks)
    qf[ks] = *reinterpret_cast<const bf16x8*>(
        &qw[((size_t)h * N_TOK + q0 + q31) * 64 + ks * 16 + hi * 8]);

  f32x16 acc0, acc1;
#pragma unroll
  for (int r = 0; r < 16; ++r) { acc0[r] = 0.f; acc1[r] = 0.f; }
  float m_run = -1e30f, l_run = 0.f;

  const int srow = t >> 3;
  const int sseg = (t & 7) * 8;

  bf16x8 kst[4], vst[4];
#pragma unroll
  for (int i = 0; i < 4; ++i) {
    const int row = srow + i * 16;
    kst[i] = *reinterpret_cast<const bf16x8*>(&kbase[(size_t)row * 64 + sseg]);
    vst[i] = *reinterpret_cast<const bf16x8*>(&vbase[(size_t)row * N_TOK + sseg]);
  }

  for (int kv = 0; kv < N_TOK; kv += 64) {
    __syncthreads();
#pragma unroll
    for (int i = 0; i < 4; ++i) {
      const int row = srow + i * 16;
      *reinterpret_cast<bf16x8*>(&Ks[row * 72 + sseg]) = kst[i];
      *reinterpret_cast<bf16x8*>(&Vs[row * 72 + sseg]) = vst[i];
    }
    __syncthreads();
    const int kvn = (kv + 64 < N_TOK) ? kv + 64 : 0;
#pragma unroll
    for (int i = 0; i < 4; ++i) {
      const int row = srow + i * 16;
      kst[i] = *reinterpret_cast<const bf16x8*>(&kbase[(size_t)(kvn + row) * 64 + sseg]);
      vst[i] = *reinterpret_cast<const bf16x8*>(&vbase[(size_t)row * N_TOK + kvn + sseg]);
    }

#pragma unroll
    for (int ct = 0; ct < 2; ++ct) {
      f32x16 s;
#pragma unroll
      for (int r = 0; r < 16; ++r) s[r] = 0.f;
#pragma unroll
      for (int ks = 0; ks < 4; ++ks) {
        const bf16x8 kf = *reinterpret_cast<const bf16x8*>(
            &Ks[(ct * 32 + q31) * 72 + ks * 16 + hi * 8]);
        s = __builtin_amdgcn_mfma_f32_32x32x16_bf16(kf, qf[ks], s, 0, 0, 0);
      }
      float pm = s[0];
#pragma unroll
      for (int r = 1; r < 16; ++r) pm = fmaxf(pm, s[r]);
      pm = fmaxf(pm, __shfl_xor(pm, 32));
      if (!__all(pm <= m_run + 8.f)) {
        const float newm = fmaxf(m_run, pm);
        const float al = __expf(m_run - newm);
        m_run = newm;
        l_run *= al;
#pragma unroll
        for (int r = 0; r < 16; ++r) {
          const float a = __shfl(al, (r & 3) + 8 * (r >> 2) + 4 * hi);
          acc0[r] *= a; acc1[r] *= a;
        }
      }
      float p[16];
      float rs = 0.f;
#pragma unroll
      for (int r = 0; r < 16; ++r) { p[r] = __expf(s[r] - m_run); rs += p[r]; }
      rs += __shfl_xor(rs, 32);
      l_run += rs;

      unsigned dw[8];
#pragma unroll
      for (int m2 = 0; m2 < 8; ++m2)
        asm("v_cvt_pk_bf16_f32 %0, %1, %2"
            : "=v"(dw[m2]) : "v"(p[2 * m2]), "v"(p[2 * m2 + 1]));
      asm("v_permlane32_swap_b32 %0, %1" : "+v"(dw[0]), "+v"(dw[2]));
      asm("v_permlane32_swap_b32 %0, %1" : "+v"(dw[1]), "+v"(dw[3]));
      asm("v_permlane32_swap_b32 %0, %1" : "+v"(dw[4]), "+v"(dw[6]));
      asm("v_permlane32_swap_b32 %0, %1" : "+v"(dw[5]), "+v"(dw[7]));

#pragma unroll
      for (int ksl = 0; ksl < 2; ++ksl) {
        u32x4 u;
        u.x = dw[ksl * 4 + 0]; u.y = dw[ksl * 4 + 1];
        u.z = dw[ksl * 4 + 2]; u.w = dw[ksl * 4 + 3];
        const bf16x8 pa = __builtin_bit_cast(bf16x8, u);
        const int kg = ct * 2 + ksl;
        const bf16x8 vf0 = *reinterpret_cast<const bf16x8*>(
            &Vs[q31 * 72 + kg * 16 + hi * 8]);
        const bf16x8 vf1 = *reinterpret_cast<const bf16x8*>(
            &Vs[(32 + q31) * 72 + kg * 16 + hi * 8]);
        acc0 = __builtin_amdgcn_mfma_f32_32x32x16_bf16(pa, vf0, acc0, 0, 0, 0);
        acc1 = __builtin_amdgcn_mfma_f32_32x32x16_bf16(pa, vf1, acc1, 0, 0, 0);
      }
    }
  }

  const float inv = 1.0f / l_run;
#pragma unroll
  for (int r = 0; r < 16; ++r) {
    const int crow = (r & 3) + 8 * (r >> 2) + 4 * hi;
    const float iv = __shfl(inv, crow);
    const size_t base = (size_t)(q0 + crow) * C_DIM + h * 64;
    ow[base + q31] = f2bf(acc0[r] * iv);
    ow[base + 32 + q31] = f2bf(acc1[r] * iv);
  }
}

extern "C" void kernel_launch(void* const* d_in, const int* in_sizes, int n_in,
                              void* d_out, int out_size, void* d_ws, size_t ws_size,
                              hipStream_t stream) {
  (void)in_sizes; (void)n_in; (void)out_size; (void)ws_size;
  const float* x = (const float*)d_in[0];
  const float* w_qkv = (const float*)d_in[1];
  const float* w_proj = (const float*)d_in[2];
  const float* b_proj = (const float*)d_in[3];
  float* out = (float*)d_out;

  const size_t HNd = (size_t)H_NUM * N_TOK * 64;  // 3145728 shorts
  unsigned short* qw = (unsigned short*)d_ws;
  unsigned short* kw = qw + HNd;
  unsigned short* vw = kw + HNd;
  unsigned short* xb = vw + HNd;        // xb region, reused as ow after gemm1
  unsigned short* ow = xb;
  unsigned short* wT = xb + HNd;        // wqkvT region, reused as wprojT
  unsigned short* wqkvT = wT;
  unsigned short* wprojT = wT;

  conv_bf16<<<dim3((N_TOK * C_DIM / 8 + 255) / 256), 256, 0, stream>>>(
      x, xb, N_TOK * C_DIM / 8);
  transpose_cvt<<<dim3(QKV_N / 64, C_DIM / 64), 256, 0, stream>>>(
      w_qkv, wqkvT, C_DIM, QKV_N);
  gemm_qkv_bf16<<<dim3(QKV_N / 128, N_TOK / 128), 256, 0, stream>>>(
      xb, wqkvT, qw, kw, vw);
  // wprojT overwrites wqkvT region; ow overwrites xb region (stream-ordered).
  transpose_cvt<<<dim3(C_DIM / 64, C_DIM / 64), 256, 0, stream>>>(
      w_proj, wprojT, C_DIM, C_DIM);
  attn_kernel<<<dim3(N_TOK / 64, H_NUM), 128, 0, stream>>>(qw, kw, vw, ow);
  gemm_proj_bf16<<<dim3(C_DIM / 128, N_TOK / 128), 256, 0, stream>>>(
      ow, wprojT, b_proj, out);
}

// Round 6
// 165.915 us; speedup vs baseline: 2.9306x; 1.0635x over previous
//
#include <hip/hip_runtime.h>

#define N_TOK 4096
#define C_DIM 768
#define H_NUM 12
#define QKV_N 2304

typedef __attribute__((ext_vector_type(8))) short bf16x8;
typedef __attribute__((ext_vector_type(4))) float f32x4;
typedef __attribute__((ext_vector_type(16))) float f32x16;
typedef __attribute__((ext_vector_type(4))) unsigned int u32x4;

static __device__ __forceinline__ unsigned short f2bf(float f) {
  unsigned u = __builtin_bit_cast(unsigned, f);
  u += 0x7FFF + ((u >> 16) & 1);   // RNE
  return (unsigned short)(u >> 16);
}

static __device__ __forceinline__ float exp2_fast(float x) {
  float r; asm("v_exp_f32 %0, %1" : "=v"(r) : "v"(x)); return r;
}

#define GLOAD_LDS16(g, l)                                                     \
  __builtin_amdgcn_global_load_lds(                                           \
      (const __attribute__((address_space(1))) void*)(g),                     \
      (__attribute__((address_space(3))) void*)(l), 16, 0, 0)

// Q prescale: 0.125 * log2(e) so attention logits are in log2 units.
#define Q_SCALE 0.18033688011112042f

// ---------------------------------------------------------------------------
// Prep 1: elementwise f32 -> bf16 (x -> xb)
// ---------------------------------------------------------------------------
__global__ __launch_bounds__(256) void conv_bf16(
    const float* __restrict__ in, unsigned short* __restrict__ out, int n8) {
  const int i = blockIdx.x * 256 + threadIdx.x;  // 8 elems per thread
  if (i >= n8) return;
  const float4 a = reinterpret_cast<const float4*>(in)[i * 2];
  const float4 b = reinterpret_cast<const float4*>(in)[i * 2 + 1];
  unsigned short tmp[8] = {f2bf(a.x), f2bf(a.y), f2bf(a.z), f2bf(a.w),
                           f2bf(b.x), f2bf(b.y), f2bf(b.z), f2bf(b.w)};
  reinterpret_cast<bf16x8*>(out)[i] = *reinterpret_cast<bf16x8*>(tmp);
}

// ---------------------------------------------------------------------------
// Prep 2: tiled transpose + convert. in f32 [K][N] -> out bf16 [N][K].
// ---------------------------------------------------------------------------
__global__ __launch_bounds__(256) void transpose_cvt(
    const float* __restrict__ in, unsigned short* __restrict__ out,
    int K, int N) {
  __shared__ unsigned short T[64][65];
  const int t = threadIdx.x;
  const int k0 = blockIdx.y * 64, n0 = blockIdx.x * 64;
  {
    const int r = t >> 2, qd = t & 3;
#pragma unroll
    for (int i = 0; i < 4; ++i) {
      const int c = qd * 16 + i * 4;
      const float4 v = *reinterpret_cast<const float4*>(
          &in[(size_t)(k0 + r) * N + n0 + c]);
      T[r][c + 0] = f2bf(v.x); T[r][c + 1] = f2bf(v.y);
      T[r][c + 2] = f2bf(v.z); T[r][c + 3] = f2bf(v.w);
    }
  }
  __syncthreads();
#pragma unroll
  for (int i = 0; i < 2; ++i) {
    const int cid = t + i * 256;
    const int rn = cid >> 3, cx = cid & 7;
    unsigned short tmp[8];
#pragma unroll
    for (int j = 0; j < 8; ++j) tmp[j] = T[cx * 8 + j][rn];
    *reinterpret_cast<bf16x8*>(&out[(size_t)(n0 + rn) * K + k0 + cx * 8]) =
        *reinterpret_cast<bf16x8*>(tmp);
  }
}

// ---------------------------------------------------------------------------
// GEMM1 (m97 structure): qkv = xb @ wqkvT^T. Epilogue scatters Q/K/V^T.
// ---------------------------------------------------------------------------
__global__ __launch_bounds__(256) void gemm_qkv_bf16(
    const unsigned short* __restrict__ A, const unsigned short* __restrict__ Bt,
    unsigned short* __restrict__ qw, unsigned short* __restrict__ kw,
    unsigned short* __restrict__ vw) {
  __shared__ unsigned short As[128 * 32];
  __shared__ unsigned short Bs[128 * 32];
  const int t = threadIdx.x;
  const int lane = t & 63, wid = t >> 6;
  const int lr = lane & 15, lg = lane >> 4;
  const int m_base = blockIdx.y * 128, n_base = blockIdx.x * 128;
  const int wm = (wid >> 1) * 64, wn = (wid & 1) * 64;
  const int c_row = lane >> 2;
  const int c_col = (lane & 3) * 8;

  f32x4 acc[4][4];
#pragma unroll
  for (int mt = 0; mt < 4; ++mt)
#pragma unroll
    for (int nt = 0; nt < 4; ++nt) acc[mt][nt] = (f32x4){0.f, 0.f, 0.f, 0.f};

  for (int kt = 0; kt < 24; ++kt) {
    const int k0 = kt * 32;
    __syncthreads();
#pragma unroll
    for (int i = 0; i < 2; ++i) {
      const int ch = wid * 2 + i;
      GLOAD_LDS16(&A[(size_t)(m_base + ch * 16 + c_row) * 768 + k0 + c_col],
                  &As[ch * 512]);
      GLOAD_LDS16(&Bt[(size_t)(n_base + ch * 16 + c_row) * 768 + k0 + c_col],
                  &Bs[ch * 512]);
    }
    __syncthreads();
    bf16x8 af[4], bfr[4];
#pragma unroll
    for (int mt = 0; mt < 4; ++mt)
      af[mt] = *reinterpret_cast<const bf16x8*>(&As[(wm + mt * 16 + lr) * 32 + lg * 8]);
#pragma unroll
    for (int nt = 0; nt < 4; ++nt)
      bfr[nt] = *reinterpret_cast<const bf16x8*>(&Bs[(wn + nt * 16 + lr) * 32 + lg * 8]);
#pragma unroll
    for (int mt = 0; mt < 4; ++mt)
#pragma unroll
      for (int nt = 0; nt < 4; ++nt)
        acc[mt][nt] = __builtin_amdgcn_mfma_f32_16x16x32_bf16(af[mt], bfr[nt],
                                                              acc[mt][nt], 0, 0, 0);
  }
#pragma unroll
  for (int mt = 0; mt < 4; ++mt)
#pragma unroll
    for (int nt = 0; nt < 4; ++nt)
#pragma unroll
      for (int r = 0; r < 4; ++r) {
        const int m = m_base + wm + mt * 16 + lg * 4 + r;
        const int c = n_base + wn + nt * 16 + lr;
        const float v = acc[mt][nt][r];
        const int which = c / 768;
        const int cc = c - which * 768;
        const int h = cc >> 6, d = cc & 63;
        if (which == 0) {
          qw[((size_t)h * N_TOK + m) * 64 + d] = f2bf(v * Q_SCALE);
        } else if (which == 1) {
          kw[((size_t)h * N_TOK + m) * 64 + d] = f2bf(v);
        } else {
          vw[((size_t)h * 64 + d) * N_TOK + m] = f2bf(v);
        }
      }
}

// ---------------------------------------------------------------------------
// GEMM2 (m97 structure): out = ow @ wprojT^T + bias. f32 out.
// ---------------------------------------------------------------------------
__global__ __launch_bounds__(256) void gemm_proj_bf16(
    const unsigned short* __restrict__ A, const unsigned short* __restrict__ Bt,
    const float* __restrict__ bias, float* __restrict__ out) {
  __shared__ unsigned short As[128 * 32];
  __shared__ unsigned short Bs[128 * 32];
  const int t = threadIdx.x;
  const int lane = t & 63, wid = t >> 6;
  const int lr = lane & 15, lg = lane >> 4;
  const int m_base = blockIdx.y * 128, n_base = blockIdx.x * 128;
  const int wm = (wid >> 1) * 64, wn = (wid & 1) * 64;
  const int c_row = lane >> 2;
  const int c_col = (lane & 3) * 8;

  f32x4 acc[4][4];
#pragma unroll
  for (int mt = 0; mt < 4; ++mt)
#pragma unroll
    for (int nt = 0; nt < 4; ++nt) acc[mt][nt] = (f32x4){0.f, 0.f, 0.f, 0.f};

  for (int kt = 0; kt < 24; ++kt) {
    const int k0 = kt * 32;
    __syncthreads();
#pragma unroll
    for (int i = 0; i < 2; ++i) {
      const int ch = wid * 2 + i;
      GLOAD_LDS16(&A[(size_t)(m_base + ch * 16 + c_row) * 768 + k0 + c_col],
                  &As[ch * 512]);
      GLOAD_LDS16(&Bt[(size_t)(n_base + ch * 16 + c_row) * 768 + k0 + c_col],
                  &Bs[ch * 512]);
    }
    __syncthreads();
    bf16x8 af[4], bfr[4];
#pragma unroll
    for (int mt = 0; mt < 4; ++mt)
      af[mt] = *reinterpret_cast<const bf16x8*>(&As[(wm + mt * 16 + lr) * 32 + lg * 8]);
#pragma unroll
    for (int nt = 0; nt < 4; ++nt)
      bfr[nt] = *reinterpret_cast<const bf16x8*>(&Bs[(wn + nt * 16 + lr) * 32 + lg * 8]);
#pragma unroll
    for (int mt = 0; mt < 4; ++mt)
#pragma unroll
      for (int nt = 0; nt < 4; ++nt)
        acc[mt][nt] = __builtin_amdgcn_mfma_f32_16x16x32_bf16(af[mt], bfr[nt],
                                                              acc[mt][nt], 0, 0, 0);
  }
#pragma unroll
  for (int nt = 0; nt < 4; ++nt) {
    const int n = n_base + wn + nt * 16 + lr;
    const float bv = bias[n];
#pragma unroll
    for (int mt = 0; mt < 4; ++mt)
#pragma unroll
      for (int r = 0; r < 4; ++r) {
        const int m = m_base + wm + mt * 16 + lg * 4 + r;
        out[(size_t)m * 768 + n] = acc[mt][nt][r] + bv;
      }
  }
}

// ---------------------------------------------------------------------------
// Flash attention v5: intra-block KV-split x2. 4 waves = (qsub x kvhalf);
// each wave does 2048 kv over its own K/V LDS pair; in-LDS merge at end.
// 32x32x16 MFMA, swapped QK^T, in-register P (cvt_pk+permlane32_swap),
// defer-max (log2 units, THR=8), prefetch staging, exp2 softmax.
// ---------------------------------------------------------------------------
__global__ __launch_bounds__(256) void attn_kernel(
    const unsigned short* __restrict__ qw, const unsigned short* __restrict__ kw,
    const unsigned short* __restrict__ vw, unsigned short* __restrict__ ow) {
  // smem: group g (kvhalf) K at [g*9216], V at [g*9216+4608] (shorts).
  // Reused at the end as the f32 merge-exchange buffer (2 x 9216 B).
  __shared__ unsigned short smem[18432];
  const int t = threadIdx.x;            // 0..255
  const int lane = t & 63;
  const int wid = t >> 6;               // 0..3
  const int qsub = wid & 1;
  const int kvh = wid >> 1;
  const int q31 = lane & 31;
  const int hi = lane >> 5;
  const int h = blockIdx.y;
  const int q0 = blockIdx.x * 64 + qsub * 32;

  unsigned short* Ks = &smem[kvh * 9216];
  unsigned short* Vs = Ks + 4608;

  const unsigned short* kbase = &kw[(size_t)h * N_TOK * 64];
  const unsigned short* vbase = &vw[(size_t)h * 64 * N_TOK];
  const int kv0 = kvh * 2048;

  // Q fragments (B-operand of 32x32x16): col = q31, k = d = ks*16 + hi*8 + j
  bf16x8 qf[4];
#pragma unroll
  for (int ks = 0; ks < 4; ++ks)
    qf[ks] = *reinterpret_cast<const bf16x8*>(
        &qw[((size_t)h * N_TOK + q0 + q31) * 64 + ks * 16 + hi * 8]);

  f32x16 acc0, acc1;
#pragma unroll
  for (int r = 0; r < 16; ++r) { acc0[r] = 0.f; acc1[r] = 0.f; }
  float m_run = -1e30f, l_run = 0.f;   // log2-units; per q=q31, dup over hi

  // staging within the 128-thread kv-group
  const int tg = t & 127;
  const int srow = tg >> 3;
  const int sseg = (tg & 7) * 8;

  bf16x8 kst[4], vst[4];
#pragma unroll
  for (int i = 0; i < 4; ++i) {
    const int row = srow + i * 16;
    kst[i] = *reinterpret_cast<const bf16x8*>(&kbase[(size_t)(kv0 + row) * 64 + sseg]);
    vst[i] = *reinterpret_cast<const bf16x8*>(&vbase[(size_t)row * N_TOK + kv0 + sseg]);
  }

  for (int kvt = 0; kvt < 32; ++kvt) {
    const int kv = kv0 + kvt * 64;
    __syncthreads();   // previous tile consumed (both groups in lockstep)
#pragma unroll
    for (int i = 0; i < 4; ++i) {
      const int row = srow + i * 16;
      *reinterpret_cast<bf16x8*>(&Ks[row * 72 + sseg]) = kst[i];
      *reinterpret_cast<bf16x8*>(&Vs[row * 72 + sseg]) = vst[i];
    }
    __syncthreads();
    // prefetch next tile (wrap -> harmless re-load of first tile)
    const int kvn = (kvt + 1 < 32) ? kv + 64 : kv0;
#pragma unroll
    for (int i = 0; i < 4; ++i) {
      const int row = srow + i * 16;
      kst[i] = *reinterpret_cast<const bf16x8*>(&kbase[(size_t)(kvn + row) * 64 + sseg]);
      vst[i] = *reinterpret_cast<const bf16x8*>(&vbase[(size_t)row * N_TOK + kvn + sseg]);
    }

#pragma unroll
    for (int ct = 0; ct < 2; ++ct) {
      f32x16 s;
#pragma unroll
      for (int r = 0; r < 16; ++r) s[r] = 0.f;
#pragma unroll
      for (int ks = 0; ks < 4; ++ks) {
        const bf16x8 kf = *reinterpret_cast<const bf16x8*>(
            &Ks[(ct * 32 + q31) * 72 + ks * 16 + hi * 8]);
        s = __builtin_amdgcn_mfma_f32_32x32x16_bf16(kf, qf[ks], s, 0, 0, 0);
      }
      // tile max: tree reduction (depth 4) + 1 cross-half shuffle
      float m8[8];
#pragma unroll
      for (int r = 0; r < 8; ++r) m8[r] = fmaxf(s[r], s[r + 8]);
#pragma unroll
      for (int r = 0; r < 4; ++r) m8[r] = fmaxf(m8[r], m8[r + 4]);
      float pm = fmaxf(fmaxf(m8[0], m8[1]), fmaxf(m8[2], m8[3]));
      pm = fmaxf(pm, __shfl_xor(pm, 32));
      // defer-max (log2 units): rescale only when max grows past THR
      if (!__all(pm <= m_run + 8.f)) {
        const float newm = fmaxf(m_run, pm);
        const float al = exp2_fast(m_run - newm);
        m_run = newm;
        l_run *= al;
#pragma unroll
        for (int r = 0; r < 16; ++r) {
          const float a = __shfl(al, (r & 3) + 8 * (r >> 2) + 4 * hi);
          acc0[r] *= a; acc1[r] *= a;
        }
      }
      float p[16];
#pragma unroll
      for (int r = 0; r < 16; ++r) p[r] = exp2_fast(s[r] - m_run);
      // tree sum
      float s8[8];
#pragma unroll
      for (int r = 0; r < 8; ++r) s8[r] = p[r] + p[r + 8];
#pragma unroll
      for (int r = 0; r < 4; ++r) s8[r] = s8[r] + s8[r + 4];
      float rs = (s8[0] + s8[1]) + (s8[2] + s8[3]);
      rs += __shfl_xor(rs, 32);
      l_run += rs;

      unsigned dw[8];
#pragma unroll
      for (int m2 = 0; m2 < 8; ++m2)
        asm("v_cvt_pk_bf16_f32 %0, %1, %2"
            : "=v"(dw[m2]) : "v"(p[2 * m2]), "v"(p[2 * m2 + 1]));
      asm("v_permlane32_swap_b32 %0, %1" : "+v"(dw[0]), "+v"(dw[2]));
      asm("v_permlane32_swap_b32 %0, %1" : "+v"(dw[1]), "+v"(dw[3]));
      asm("v_permlane32_swap_b32 %0, %1" : "+v"(dw[4]), "+v"(dw[6]));
      asm("v_permlane32_swap_b32 %0, %1" : "+v"(dw[5]), "+v"(dw[7]));

#pragma unroll
      for (int ksl = 0; ksl < 2; ++ksl) {
        u32x4 u;
        u.x = dw[ksl * 4 + 0]; u.y = dw[ksl * 4 + 1];
        u.z = dw[ksl * 4 + 2]; u.w = dw[ksl * 4 + 3];
        const bf16x8 pa = __builtin_bit_cast(bf16x8, u);
        const int kg = ct * 2 + ksl;
        const bf16x8 vf0 = *reinterpret_cast<const bf16x8*>(
            &Vs[q31 * 72 + kg * 16 + hi * 8]);
        const bf16x8 vf1 = *reinterpret_cast<const bf16x8*>(
            &Vs[(32 + q31) * 72 + kg * 16 + hi * 8]);
        acc0 = __builtin_amdgcn_mfma_f32_32x32x16_bf16(pa, vf0, acc0, 0, 0, 0);
        acc1 = __builtin_amdgcn_mfma_f32_32x32x16_bf16(pa, vf1, acc1, 0, 0, 0);
      }
    }
  }

  // ---- intra-block merge of the two kv halves (in LDS, f32) ----
  __syncthreads();                       // all compute done; LDS reusable
  float* ex = reinterpret_cast<float*>(smem) + qsub * 2304;  // 9216 B per pair
  if (kvh == 1) {
    float* pdst = ex + lane * 36;
#pragma unroll
    for (int r = 0; r < 16; ++r) { pdst[r] = acc0[r]; pdst[16 + r] = acc1[r]; }
    pdst[32] = m_run;
    pdst[33] = l_run;
  }
  __syncthreads();
  if (kvh == 0) {
    const float* psrc = ex + lane * 36;
    const float mB = psrc[32], lB = psrc[33];
    const float m2 = fmaxf(m_run, mB);
    const float fA = exp2_fast(m_run - m2);
    const float fB = exp2_fast(mB - m2);
    const float linv = 1.0f / (l_run * fA + lB * fB);
    const float gA = fA * linv, gB = fB * linv;
#pragma unroll
    for (int r = 0; r < 16; ++r) {
      const int crow = (r & 3) + 8 * (r >> 2) + 4 * hi;
      const float a = __shfl(gA, crow);
      const float b = __shfl(gB, crow);
      const size_t base = (size_t)(q0 + crow) * C_DIM + h * 64;
      ow[base + q31] = f2bf(acc0[r] * a + psrc[r] * b);
      ow[base + 32 + q31] = f2bf(acc1[r] * a + psrc[16 + r] * b);
    }
  }
}

extern "C" void kernel_launch(void* const* d_in, const int* in_sizes, int n_in,
                              void* d_out, int out_size, void* d_ws, size_t ws_size,
                              hipStream_t stream) {
  (void)in_sizes; (void)n_in; (void)out_size; (void)ws_size;
  const float* x = (const float*)d_in[0];
  const float* w_qkv = (const float*)d_in[1];
  const float* w_proj = (const float*)d_in[2];
  const float* b_proj = (const float*)d_in[3];
  float* out = (float*)d_out;

  const size_t HNd = (size_t)H_NUM * N_TOK * 64;  // 3145728 shorts
  unsigned short* qw = (unsigned short*)d_ws;
  unsigned short* kw = qw + HNd;
  unsigned short* vw = kw + HNd;
  unsigned short* xb = vw + HNd;        // xb region, reused as ow after gemm1
  unsigned short* ow = xb;
  unsigned short* wT = xb + HNd;        // wqkvT region, reused as wprojT
  unsigned short* wqkvT = wT;
  unsigned short* wprojT = wT;

  conv_bf16<<<dim3((N_TOK * C_DIM / 8 + 255) / 256), 256, 0, stream>>>(
      x, xb, N_TOK * C_DIM / 8);
  transpose_cvt<<<dim3(QKV_N / 64, C_DIM / 64), 256, 0, stream>>>(
      w_qkv, wqkvT, C_DIM, QKV_N);
  gemm_qkv_bf16<<<dim3(QKV_N / 128, N_TOK / 128), 256, 0, stream>>>(
      xb, wqkvT, qw, kw, vw);
  // wprojT overwrites wqkvT region; ow overwrites xb region (stream-ordered).
  transpose_cvt<<<dim3(C_DIM / 64, C_DIM / 64), 256, 0, stream>>>(
      w_proj, wprojT, C_DIM, C_DIM);
  attn_kernel<<<dim3(N_TOK / 64, H_NUM), 256, 0, stream>>>(qw, kw, vw, ow);
  gemm_proj_bf16<<<dim3(C_DIM / 128, N_TOK / 128), 256, 0, stream>>>(
      ow, wprojT, b_proj, out);
}